// Round 1
// 212.548 us; speedup vs baseline: 1.2117x; 1.2117x over previous
//
#include <hip/hip_runtime.h>
#include <hip/hip_bf16.h>

// Problem constants
#define B_ 8
#define S_ 4096
#define H_ 512

using short8 = __attribute__((ext_vector_type(8))) short;
using f32x4  = __attribute__((ext_vector_type(4))) float;

// ---------- helpers ----------
__device__ __forceinline__ float bf2f(unsigned u16) {
    return __uint_as_float(u16 << 16);
}
__device__ __forceinline__ unsigned pk2bf(float x, float y) {
    __hip_bfloat162 h = __float22bfloat162_rn(make_float2(x, y));  // v_cvt_pk_bf16_f32
    return *reinterpret_cast<unsigned*>(&h);
}
__device__ __forceinline__ float softplus_f(float x) {
    float sp = __logf(1.0f + __expf(x));
    return x > 15.0f ? x : sp;
}

// async global->LDS, 16B per lane; LDS dest = wave-uniform base + lane*16
typedef __attribute__((address_space(1))) void* gbl_ptr_t;
typedef __attribute__((address_space(3))) void* lds_ptr_t;
__device__ __forceinline__ void gload_lds16(const void* g, void* l) {
    __builtin_amdgcn_global_load_lds((gbl_ptr_t)g, (lds_ptr_t)l, 16, 0, 0);
}

// ---------- Pass 1: one-shot fp32 -> bf16 conversion of A (lstm) and W ----------
// A: 16,777,216 elems ; W: 524,288 elems ; 8 elems/thread.
#define ASZ8 2097152u   // A elems / 8
#define TOT8 2162688u   // (A + W elems) / 8  -> 8448 blocks * 256 threads

__global__ __launch_bounds__(256)
void convert_bf16(const float* __restrict__ A, const float* __restrict__ Wm,
                  uint4* __restrict__ Ab, uint4* __restrict__ Wb) {
    unsigned i = blockIdx.x * 256u + threadIdx.x;
    const float4* src; uint4* dst; unsigned off;
    if (i < ASZ8) { src = (const float4*)A;  dst = Ab; off = i; }
    else          { src = (const float4*)Wm; dst = Wb; off = i - ASZ8; }
    float4 a = src[2u * off], b = src[2u * off + 1u];
    uint4 o;
    o.x = pk2bf(a.x, a.y); o.y = pk2bf(a.z, a.w);
    o.z = pk2bf(b.x, b.y); o.w = pk2bf(b.z, b.w);
    dst[off] = o;
}

// ---------- Pass 2: bf16 GEMM + bias + softplus, packed {q,r} uint stores ----------
// C(32768x1024) = A(32768x512) * W(1024x512)^T ; q = n<512 cols, r = n>=512 cols.
// 128x128 tile, BK=64, 4 waves (2x2 of 64x64), global_load_lds w/ XOR-swizzled
// content (linear dest + inverse-swizzled source + swizzled ds_read: rule #21).
#define TM 128
#define TN 128
#define BK 64

__global__ __launch_bounds__(256)
void gemm_softplus(const unsigned short* __restrict__ Ab,
                   const unsigned short* __restrict__ Wb,
                   const float* __restrict__ bias,
                   unsigned* __restrict__ QR) {
    __shared__ unsigned short As[TM * BK];   // 16 KB, linear (required by gload_lds)
    __shared__ unsigned short Bs[TN * BK];   // 16 KB

    // XCD-chunked swizzle: 2048 blocks = 8 XCD * 256; the 8 blocks sharing an
    // A strip (logical j..j+7) land on ONE XCD -> strip read once per XCD L2.
    const int bid     = blockIdx.x;
    const int logical = (bid & 7) * 256 + (bid >> 3);
    const int bm = logical >> 3;     // 0..255
    const int bn = logical & 7;      // 0..7

    const int t    = threadIdx.x;
    const int wave = t >> 6;
    const int lane = t & 63;
    const int wm  = (wave >> 1) * 64;
    const int wn  = (wave & 1) * 64;
    const int l15 = lane & 15;
    const int l4  = lane >> 4;

    const int m0 = bm * TM;

    // staging lane geometry: issue j covers rows j*8..j*8+7 (128B each);
    // lane writes 16B slot (lane&7) of row j*8+(lane>>3). Content swizzle:
    // slot u' holds logical unit u = u' ^ (row&7)  (row&7 == lane>>3 here).
    const int lr = lane >> 3;
    const int su = ((lane & 7) ^ lr) * 8;    // source k-offset (bf16 elems)

    f32x4 acc[4][4] = {};

    for (int kc = 0; kc < 512; kc += BK) {
#pragma unroll
        for (int i = 0; i < 4; ++i) {
            const int j   = wave * 4 + i;    // issue 0..15
            const int row = j * 8 + lr;
            gload_lds16(Ab + (size_t)(m0 + row) * 512 + kc + su, &As[j * 512]);
            // B tile row -> W row: rows 0..31 -> q cols bn*64+0..31,
            // 32..63 -> same +512 (r), 64..95 -> q cols +32, 96..127 -> r +32.
            const int n = bn * 64 + (row & 31) + ((row & 64) >> 1) + ((row & 32) << 4);
            gload_lds16(Wb + (size_t)n * 512 + kc + su, &Bs[j * 512]);
        }
        __syncthreads();   // drains vmcnt(0) for gload_lds + barrier

#pragma unroll
        for (int kk = 0; kk < 2; ++kk) {
            short8 af[4], bf[4];
#pragma unroll
            for (int i = 0; i < 4; ++i) {
                const int ra = wm + i * 16 + l15;
                const int ua = ((kk * 4 + l4) ^ (ra & 7)) * 8;
                af[i] = *(const short8*)&As[ra * 64 + ua];
                const int rb = wn + i * 16 + l15;
                const int ub = ((kk * 4 + l4) ^ (rb & 7)) * 8;
                bf[i] = *(const short8*)&Bs[rb * 64 + ub];
            }
#pragma unroll
            for (int i = 0; i < 4; ++i)
#pragma unroll
                for (int j = 0; j < 4; ++j)
                    acc[i][j] = __builtin_amdgcn_mfma_f32_16x16x32_bf16(af[i], bf[j], acc[i][j], 0, 0, 0);
        }
        __syncthreads();
    }

    // epilogue: thread owns q in acc[i][j] (j=0,1) and matching r in acc[i][j+2]
    // -> packed 4B {q,r} store, full write-sector density (fixes 2x WRITE_SIZE).
#pragma unroll
    for (int j = 0; j < 2; ++j) {
        const int h  = bn * 64 + (wn >> 1) + j * 16 + l15;  // 0..511
        const float bq = bias[h];
        const float br = bias[h + 512];
#pragma unroll
        for (int i = 0; i < 4; ++i) {
            const int mb = m0 + wm + i * 16 + l4 * 4;
#pragma unroll
            for (int r = 0; r < 4; ++r) {
                const float qv = softplus_f(acc[i][j][r] + bq);
                const float rv = softplus_f(acc[i][j + 2][r] + br);
                QR[(size_t)(mb + r) * 512 + h] = pk2bf(qv, rv);
            }
        }
    }
}

// ---------- Pass 3: chunked Kalman scan ----------
// 64 chunks of 64 steps, 64-step warm-up (decay ~e^-25, far below tolerance).
// Each thread owns 2 h-columns: 8B loads, 2 independent dep-chains (2x ILP).
// 4-buffer pipeline, prefetch depth 2, all static register indexing.
#define CHUNK 64
#define WARM 64

__global__ __launch_bounds__(256)
void kalman_scan(const float* __restrict__ z,
                 const unsigned* __restrict__ QR,
                 float* __restrict__ out) {
    const int t     = threadIdx.x;
    const int b     = blockIdx.x & 7;
    const int chunk = blockIdx.x >> 3;          // 0..63
    const int h     = t * 2;
    const int s0    = chunk << 6;
    const int sw    = (chunk == 0) ? 0 : (s0 - WARM);
    const size_t base = ((size_t)(b * S_ + sw)) * 512 + h;

    const float2* zp  = (const float2*)(z + base);    // stride 256 float2 / step
    const uint2*  qrp = (const uint2*)(QR + base);
    float2*       op  = (float2*)(out + base);

    const int ng    = ((s0 + CHUNK) - sw) >> 3;   // 8 (chunk 0) or 16
    const int skipg = (s0 - sw) >> 3;             // 0 or 8

    float2 Z0[8], Z1[8], Z2[8], Z3[8];
    uint2  Q0[8], Q1[8], Q2[8], Q3[8];

#define LOADG(g, Zb, Qb) { const int _o = (g) * 8;                          \
    _Pragma("unroll") for (int u = 0; u < 8; ++u) {                         \
        Zb[u] = zp[(_o + u) * 256]; Qb[u] = qrp[(_o + u) * 256]; } }

#define COMP(g, Zb, Qb) { const int _o = (g) * 8; const bool _st = (g) >= skipg; \
    _Pragma("unroll") for (int u = 0; u < 8; ++u) {                         \
        const unsigned qx = Qb[u].x, qy = Qb[u].y;                          \
        const float q0 = bf2f(qx & 0xffffu), r0 = bf2f(qx >> 16);           \
        const float q1 = bf2f(qy & 0xffffu), r1 = bf2f(qy >> 16);           \
        const float2 zv = Zb[u];                                            \
        const float Pp0 = P0 + q0, rr0 = r0 + 1e-6f;                        \
        const float K0  = Pp0 * __builtin_amdgcn_rcpf(Pp0 + rr0);           \
        st0 = fmaf(K0, zv.x - st0, st0); P0 = rr0 * K0;                     \
        const float Pp1 = P1 + q1, rr1 = r1 + 1e-6f;                        \
        const float K1  = Pp1 * __builtin_amdgcn_rcpf(Pp1 + rr1);           \
        st1 = fmaf(K1, zv.y - st1, st1); P1 = rr1 * K1;                     \
        if (_st) op[(_o + u) * 256] = make_float2(st0, st1); } }

    LOADG(0, Z0, Q0);
    LOADG(1, Z1, Q1);

    float st0 = Z0[0].x, st1 = Z0[0].y;   // state init = z[sw]
    float P0 = 0.1f, P1 = 0.1f;

    for (int gq = 0; gq < ng; gq += 4) {
        if (gq + 2 < ng) LOADG(gq + 2, Z2, Q2);
        COMP(gq, Z0, Q0);
        if (gq + 3 < ng) LOADG(gq + 3, Z3, Q3);
        COMP(gq + 1, Z1, Q1);
        if (gq + 4 < ng) LOADG(gq + 4, Z0, Q0);
        COMP(gq + 2, Z2, Q2);
        if (gq + 5 < ng) LOADG(gq + 5, Z1, Q1);
        COMP(gq + 3, Z3, Q3);
    }
#undef LOADG
#undef COMP
}

extern "C" void kernel_launch(void* const* d_in, const int* in_sizes, int n_in,
                              void* d_out, int out_size, void* d_ws, size_t ws_size,
                              hipStream_t stream) {
    const float* lstm = (const float*)d_in[0];   // (8,4096,512) fp32
    const float* Wm   = (const float*)d_in[1];   // (1024,512)  fp32
    const float* bias = (const float*)d_in[2];   // (1024,)     fp32
    float* out = (float*)d_out;

    unsigned* QRw = (unsigned*)d_ws;             // packed {q,r} bf16x2, 64 MB

    // d_out (64 MB) is dead until the scan writes it -> use as bf16 scratch:
    // Ab = 32 MB at offset 0, Wb = 1 MB at offset 32 MB.
    unsigned short* Abf = (unsigned short*)d_out;
    unsigned short* Wbf = (unsigned short*)((char*)d_out + (32u << 20));

    hipLaunchKernelGGL(convert_bf16, dim3(8448), dim3(256), 0, stream,
                       lstm, Wm, (uint4*)Abf, (uint4*)Wbf);

    hipLaunchKernelGGL(gemm_softplus, dim3(2048), dim3(256), 0, stream,
                       Abf, Wbf, bias, QRw);

    // 8 batches * 64 chunks = 512 blocks of 256 threads (2 blocks/CU)
    hipLaunchKernelGGL(kalman_scan, dim3(512), dim3(256), 0, stream,
                       lstm, QRw, out);
}

// Round 4
// 201.166 us; speedup vs baseline: 1.2803x; 1.0566x over previous
//
#include <hip/hip_runtime.h>
#include <hip/hip_bf16.h>

// Problem constants
#define B_ 8
#define S_ 4096
#define H_ 512

using short8 = __attribute__((ext_vector_type(8))) short;
using f32x4  = __attribute__((ext_vector_type(4))) float;

// ---------- helpers ----------
__device__ __forceinline__ float bf2f(unsigned u16) {
    return __uint_as_float(u16 << 16);
}
__device__ __forceinline__ unsigned pk2bf(float x, float y) {
    __hip_bfloat162 h = __float22bfloat162_rn(make_float2(x, y));  // v_cvt_pk_bf16_f32
    return *reinterpret_cast<unsigned*>(&h);
}
__device__ __forceinline__ float softplus_f(float x) {
    float sp = __logf(1.0f + __expf(x));
    return x > 15.0f ? x : sp;
}

// async global->LDS, 16B per lane; LDS dest = wave-uniform base + lane*16
typedef __attribute__((address_space(1))) void* gbl_ptr_t;
typedef __attribute__((address_space(3))) void* lds_ptr_t;
__device__ __forceinline__ void gload_lds16(const void* g, void* l) {
    __builtin_amdgcn_global_load_lds((gbl_ptr_t)g, (lds_ptr_t)l, 16, 0, 0);
}

// raw barrier (no vmcnt/lgkmcnt drain) with compiler memory fences
#define BAR() do { asm volatile("" ::: "memory"); \
                   __builtin_amdgcn_s_barrier(); \
                   asm volatile("" ::: "memory"); } while (0)

// lgkmcnt(0) wait + scheduling fence (rule #18: MFMA is register-only and
// hipcc will hoist it past an asm waitcnt unless sched_barrier(0) follows)
#define WAIT_LGKM0() do { asm volatile("s_waitcnt lgkmcnt(0)" ::: "memory"); \
                          __builtin_amdgcn_sched_barrier(0); } while (0)

// ---------- Pass 1: one-shot fp32 -> bf16 conversion of A (lstm) and W ----------
#define ASZ8 2097152u   // A elems / 8
#define TOT8 2162688u   // (A + W elems) / 8

__global__ __launch_bounds__(256)
void convert_bf16(const float* __restrict__ A, const float* __restrict__ Wm,
                  uint4* __restrict__ Ab, uint4* __restrict__ Wb) {
    for (unsigned i = blockIdx.x * 256u + threadIdx.x; i < TOT8; i += 2048u * 256u) {
        const float4* src; uint4* dst; unsigned off;
        if (i < ASZ8) { src = (const float4*)A;  dst = Ab; off = i; }
        else          { src = (const float4*)Wm; dst = Wb; off = i - ASZ8; }
        float4 a = src[2u * off], b = src[2u * off + 1u];
        uint4 o;
        o.x = pk2bf(a.x, a.y); o.y = pk2bf(a.z, a.w);
        o.z = pk2bf(b.x, b.y); o.w = pk2bf(b.z, b.w);
        dst[off] = o;
    }
}

// ---------- Pass 2: 128x128 bf16 GEMM, 2-slot LDS ring, counted vmcnt ----------
// IDENTICAL memory geometry to the round-1 kernel that passed (staging swizzle,
// B q/r row remap, ds_read swizzle, epilogue, 2048x256 launch, 64 KB LDS).
// Only the sync structure changes: K = 8 slices of 64; double-buffered slots;
// STAGE(g+1) issued before compute of slice g; raw s_barrier (no drain);
// steady-state s_waitcnt vmcnt(8) = next slice's 8 loads stay in flight.
// Slot-reuse safety: each wave does lgkmcnt(0) after its last ds_read of a
// slice before the slice-end barrier; the overwriting STAGE(g+2) is issued
// only after that barrier -> no wave can see a partially-overwritten slot.
#define TM 128
#define TN 128
#define BK 64

__global__ __launch_bounds__(256, 2)
void gemm_softplus(const unsigned short* __restrict__ Ab,
                   const unsigned short* __restrict__ Wb,
                   const float* __restrict__ bias,
                   unsigned* __restrict__ QR) {
    __shared__ unsigned short As[2][8192];   // 2 slots x (128 rows x 64 bf16) = 32 KB
    __shared__ unsigned short Bs[2][8192];   // 32 KB   (total 64 KB, 2 blocks/CU)

    // XCD-chunked swizzle: 2048 blocks = 8 XCD * 256; the 8 blocks sharing an
    // A strip land on ONE XCD (round-1 measured: FETCH 265 -> 22 MB).
    const int bid     = blockIdx.x;
    const int logical = (bid & 7) * 256 + (bid >> 3);
    const int bm = logical >> 3;     // 0..255
    const int bn = logical & 7;      // 0..7

    const int t    = threadIdx.x;
    const int wave = t >> 6;
    const int lane = t & 63;
    const int wm  = (wave >> 1) * 64;
    const int wn  = (wave & 1) * 64;
    const int l15 = lane & 15;
    const int l4  = lane >> 4;

    const int m0 = bm * TM;

    // staging lane geometry (round-1 verified): issue j covers rows j*8..j*8+7,
    // lane writes 16B slot (lane&7) of row j*8+(lane>>3); content swizzle:
    // slot u' holds source k-chunk u' ^ (row&7)  (row&7 == lane>>3 here).
    const int lr = lane >> 3;
    const int su = ((lane & 7) ^ lr) * 8;    // inverse-swizzled source k offset

    const unsigned short* agp[4];
    const unsigned short* bgp[4];
    int ldsoff[4];
#pragma unroll
    for (int i = 0; i < 4; ++i) {
        const int j   = wave * 4 + i;        // issue 0..15
        const int row = j * 8 + lr;          // tile row 0..127
        agp[i] = Ab + (size_t)(m0 + row) * 512 + su;
        // B tile row -> W row: rows 0..31 -> q cols bn*64+0..31, 32..63 -> same
        // +512 (r), 64..95 -> q cols +32, 96..127 -> r cols +32 (packed epilogue).
        const int n = bn * 64 + (row & 31) + ((row & 64) >> 1) + ((row & 32) << 4);
        bgp[i] = Wb + (size_t)n * 512 + su;
        ldsoff[i] = j * 512;                 // wave-uniform LDS dest (shorts)
    }

    f32x4 acc[4][4] = {};

#define STAGE(s) do { \
    const int _sl = (s) & 1; const int _kc = (s) * BK; \
    _Pragma("unroll") for (int i = 0; i < 4; ++i) { \
        gload_lds16(agp[i] + _kc, &As[_sl][ldsoff[i]]); \
        gload_lds16(bgp[i] + _kc, &Bs[_sl][ldsoff[i]]); \
    } \
} while (0)

#define COMPUTE(g, VMN) do { \
    const unsigned short* _a = &As[(g) & 1][0]; \
    const unsigned short* _b = &Bs[(g) & 1][0]; \
    asm volatile("s_waitcnt vmcnt(" #VMN ")" ::: "memory"); \
    BAR(); \
    _Pragma("unroll") for (int kk = 0; kk < 2; ++kk) { \
        short8 af[4], bf[4]; \
        _Pragma("unroll") for (int i = 0; i < 4; ++i) { \
            const int ra = wm + i * 16 + l15; \
            af[i] = *(const short8*)(_a + ra * 64 + (((kk * 4 + l4) ^ (ra & 7)) * 8)); \
            const int rb = wn + i * 16 + l15; \
            bf[i] = *(const short8*)(_b + rb * 64 + (((kk * 4 + l4) ^ (rb & 7)) * 8)); \
        } \
        WAIT_LGKM0(); \
        __builtin_amdgcn_s_setprio(1); \
        _Pragma("unroll") for (int i = 0; i < 4; ++i) \
        _Pragma("unroll") for (int j = 0; j < 4; ++j) \
            acc[i][j] = __builtin_amdgcn_mfma_f32_16x16x32_bf16(af[i], bf[j], acc[i][j], 0, 0, 0); \
        __builtin_amdgcn_s_setprio(0); \
    } \
    BAR(); \
} while (0)

    STAGE(0);                                   // 8 loads in flight
    for (int g = 0; g < 7; ++g) {
        STAGE(g + 1);                           // 16 in flight
        COMPUTE(g, 8);                          // wait slice g only; g+1 stays in flight
    }
    COMPUTE(7, 0);                              // final slice: full drain is free

#undef COMPUTE
#undef STAGE

    // epilogue (round-1 verified): bias + softplus, packed {q,r} 4B stores
#pragma unroll
    for (int j = 0; j < 2; ++j) {
        const int h  = bn * 64 + (wn >> 1) + j * 16 + l15;  // 0..511
        const float bq = bias[h];
        const float br = bias[h + 512];
#pragma unroll
        for (int i = 0; i < 4; ++i) {
            const int mb = m0 + wm + i * 16 + l4 * 4;
#pragma unroll
            for (int r = 0; r < 4; ++r) {
                const float qv = softplus_f(acc[i][j][r] + bq);
                const float rv = softplus_f(acc[i][j + 2][r] + br);
                QR[(size_t)(mb + r) * 512 + h] = pk2bf(qv, rv);
            }
        }
    }
}

// ---------- Pass 3: chunked Kalman scan ----------
// 32 chunks of 128 steps, 64-step warm-up (history >= round-1's passing config).
// 1 h-column/thread, 8-buffer rotation, prefetch depth 4 groups.
// ng in {16,24}, both multiples of 8 -> unguarded COMP.
#define CHUNK 128
#define WARM 64

__global__ __launch_bounds__(256, 2)
void kalman_scan(const float* __restrict__ z,
                 const unsigned* __restrict__ QR,
                 float* __restrict__ out) {
    const int t     = threadIdx.x;
    const int hb    = blockIdx.x & 1;
    const int b     = (blockIdx.x >> 1) & 7;
    const int chunk = blockIdx.x >> 4;          // 0..31
    const int h     = hb * 256 + t;             // 0..511
    const int s0    = chunk << 7;               // chunk*128
    const int sw    = (chunk == 0) ? 0 : (s0 - WARM);
    const size_t base = ((size_t)(b * S_ + sw)) * 512 + h;

    const float*    zp  = z + base;             // stride 512 floats / step
    const unsigned* qrp = (const unsigned*)QR + base;
    float*          op  = out + base;

    const int ng    = ((s0 + CHUNK) - sw) >> 3;   // 16 (chunk 0) or 24
    const int skipg = (s0 - sw) >> 3;             // 0 or 8

    float    Z0[8], Z1[8], Z2[8], Z3[8], Z4[8], Z5[8], Z6[8], Z7[8];
    unsigned Q0[8], Q1[8], Q2[8], Q3[8], Q4[8], Q5[8], Q6[8], Q7[8];

#define LOADG(g, Zb, Qb) { const int _o = (g) * 8;                          \
    _Pragma("unroll") for (int u = 0; u < 8; ++u) {                         \
        Zb[u] = zp[(size_t)(_o + u) * 512]; Qb[u] = qrp[(size_t)(_o + u) * 512]; } }

#define COMP(g, Zb, Qb) { const int _o = (g) * 8; const bool _st = (g) >= skipg; \
    _Pragma("unroll") for (int u = 0; u < 8; ++u) {                         \
        const float q  = bf2f(Qb[u] & 0xffffu);                             \
        const float r  = bf2f(Qb[u] >> 16);                                 \
        const float Pp = P + q, rr = r + 1e-6f;                             \
        const float K  = Pp * __builtin_amdgcn_rcpf(Pp + rr);               \
        state = fmaf(K, Zb[u] - state, state); P = rr * K;                  \
        if (_st) op[(size_t)(_o + u) * 512] = state; } }

    LOADG(0, Z0, Q0); LOADG(1, Z1, Q1); LOADG(2, Z2, Q2); LOADG(3, Z3, Q3);

    float state = Z0[0];   // state init = z[sw]
    float P = 0.1f;

    for (int g = 0; g < ng; g += 8) {
        if (g + 4  < ng) LOADG(g + 4,  Z4, Q4); COMP(g,     Z0, Q0);
        if (g + 5  < ng) LOADG(g + 5,  Z5, Q5); COMP(g + 1, Z1, Q1);
        if (g + 6  < ng) LOADG(g + 6,  Z6, Q6); COMP(g + 2, Z2, Q2);
        if (g + 7  < ng) LOADG(g + 7,  Z7, Q7); COMP(g + 3, Z3, Q3);
        if (g + 8  < ng) LOADG(g + 8,  Z0, Q0); COMP(g + 4, Z4, Q4);
        if (g + 9  < ng) LOADG(g + 9,  Z1, Q1); COMP(g + 5, Z5, Q5);
        if (g + 10 < ng) LOADG(g + 10, Z2, Q2); COMP(g + 6, Z6, Q6);
        if (g + 11 < ng) LOADG(g + 11, Z3, Q3); COMP(g + 7, Z7, Q7);
    }
#undef LOADG
#undef COMP
}

extern "C" void kernel_launch(void* const* d_in, const int* in_sizes, int n_in,
                              void* d_out, int out_size, void* d_ws, size_t ws_size,
                              hipStream_t stream) {
    const float* lstm = (const float*)d_in[0];   // (8,4096,512) fp32
    const float* Wm   = (const float*)d_in[1];   // (1024,512)  fp32
    const float* bias = (const float*)d_in[2];   // (1024,)     fp32

    unsigned* QRw = (unsigned*)d_ws;             // packed {q,r} bf16x2, 64 MB

    // d_out (64 MB) is dead until the scan writes it -> bf16 scratch:
    // Ab = 32 MB at offset 0, Wb = 1 MB at offset 32 MB.
    unsigned short* Abf = (unsigned short*)d_out;
    unsigned short* Wbf = (unsigned short*)((char*)d_out + (32u << 20));

    hipLaunchKernelGGL(convert_bf16, dim3(2048), dim3(256), 0, stream,
                       lstm, Wm, (uint4*)Abf, (uint4*)Wbf);

    // 256 M-tiles x 8 N-tiles = 2048 blocks of 256 threads
    hipLaunchKernelGGL(gemm_softplus, dim3(2048), dim3(256), 0, stream,
                       Abf, Wbf, bias, QRw);

    // 2 h-halves * 8 batches * 32 chunks = 512 blocks of 256 threads (2/CU)
    hipLaunchKernelGGL(kalman_scan, dim3(512), dim3(256), 0, stream,
                       lstm, QRw, (float*)d_out);
}